// Round 1
// baseline (416.672 us; speedup 1.0000x reference)
//
#include <hip/hip_runtime.h>
#include <hip/hip_bf16.h>

typedef __attribute__((ext_vector_type(8))) short short8v;   // 8 bf16 (4 VGPRs)
typedef __attribute__((ext_vector_type(4))) float f32x4;
typedef __attribute__((ext_vector_type(4))) int int4v;

#define NTOK  2048
#define NEMBD 768
#define DFF   3072
#define NEXP  8
#define MAXSLOT 4608   // 4096 assignments + 8*63 pad, rounded

// ---- workspace layout (bytes) ----
#define WS_XBF   0                                  // ushort [2048][768]
#define WS_GATES (WS_XBF + NTOK*NEMBD*2)            // float  [2048][8]
#define WS_TE    (WS_GATES + NTOK*8*4)              // int    [2048][2]
#define WS_TW    (WS_TE + NTOK*2*4)                 // float  [2048][2]
#define WS_KL    (WS_TW + NTOK*2*4)                 // float  [2048]
#define WS_CTRL  (WS_KL + NTOK*4)                   // int[32]: 0-7 counts, 8-15 cursors, 16-24 offsets
#define WS_STOK  (WS_CTRL + 128)                    // int    [MAXSLOT]
#define WS_SGATE (WS_STOK + MAXSLOT*4)              // float  [MAXSLOT]
#define WS_SRANK (WS_SGATE + MAXSLOT*4)             // int    [MAXSLOT]
#define WS_H     (WS_SRANK + MAXSLOT*4)             // ushort [MAXSLOT][3072]
#define WS_OUT   (WS_H + (size_t)MAXSLOT*DFF*2)     // float  [2][2048][768]
// total ~44.2 MB

__device__ __forceinline__ unsigned short f2bf(float f) {
    union { float f; unsigned u; } v; v.f = f;
    unsigned r = v.u + 0x7fffu + ((v.u >> 16) & 1u);   // RNE
    return (unsigned short)(r >> 16);
}

// ---------------- router: logits (fp32), softmax, top2, KL, x->bf16 ----------------
__global__ __launch_bounds__(256) void k_router(
    const float* __restrict__ x, const float* __restrict__ WgP, const float* __restrict__ WgQ,
    unsigned short* __restrict__ xbf, float* __restrict__ gates,
    int* __restrict__ te, float* __restrict__ tw, float* __restrict__ kl_tok,
    int* __restrict__ ctrl)
{
    __shared__ float sWp[NEMBD * NEXP];   // 24 KB
    __shared__ float sWq[NEMBD * NEXP];   // 24 KB
    int tid = threadIdx.x;
    for (int i = tid; i < NEMBD * NEXP; i += 256) { sWp[i] = WgP[i]; sWq[i] = WgQ[i]; }
    __syncthreads();

    int wave = tid >> 6, lane = tid & 63;
    // 128 blocks x 16 tokens
    for (int it = 0; it < 4; ++it) {
        int t = blockIdx.x * 16 + it * 4 + wave;
        int b = t >> 10, l = t & 1023;
        int lf = l + 2; if (lf > 1023) lf = 1023;           // lookforward pad-with-last
        const float* xr = x + (size_t)t * NEMBD;
        const float* xf = x + ((size_t)((b << 10) + lf)) * NEMBD;
        float accP[NEXP], accQ[NEXP];
        #pragma unroll
        for (int e = 0; e < NEXP; ++e) { accP[e] = 0.f; accQ[e] = 0.f; }
        for (int k = lane; k < NEMBD; k += 64) {
            float xv = xr[k], xfv = xf[k];
            #pragma unroll
            for (int e = 0; e < NEXP; ++e) {
                accP[e] += xv  * sWp[k * NEXP + e];
                accQ[e] += xfv * sWq[k * NEXP + e];
            }
        }
        #pragma unroll
        for (int e = 0; e < NEXP; ++e) {
            #pragma unroll
            for (int off = 32; off; off >>= 1) {
                accP[e] += __shfl_xor(accP[e], off);
                accQ[e] += __shfl_xor(accQ[e], off);
            }
        }
        if (lane == 0) {
            float mq = accQ[0], mp = accP[0];
            #pragma unroll
            for (int e = 1; e < NEXP; ++e) { mq = fmaxf(mq, accQ[e]); mp = fmaxf(mp, accP[e]); }
            float g[NEXP], se = 0.f, sp = 0.f;
            #pragma unroll
            for (int e = 0; e < NEXP; ++e) {
                g[e] = __expf(accQ[e] - mq); se += g[e];
                sp += __expf(accP[e] - mp);
            }
            float inv_se = 1.f / se;
            #pragma unroll
            for (int e = 0; e < NEXP; ++e) gates[t * NEXP + e] = g[e] * inv_se;
            // top-2 (ties: lowest index first, matches lax.top_k)
            int e0 = 0;
            #pragma unroll
            for (int e = 1; e < NEXP; ++e) if (g[e] > g[e0]) e0 = e;
            int e1 = (e0 == 0) ? 1 : 0;
            #pragma unroll
            for (int e = 0; e < NEXP; ++e) if (e != e0 && g[e] > g[e1]) e1 = e;
            float s2 = g[e0] + g[e1];
            te[t * 2] = e0; te[t * 2 + 1] = e1;
            tw[t * 2] = g[e0] / s2; tw[t * 2 + 1] = g[e1] / s2;
            atomicAdd(&ctrl[e0], 1); atomicAdd(&ctrl[e1], 1);
            // KL(post || prior)
            float lseQ = mq + logf(se), lseP = mp + logf(sp);
            float kl = 0.f;
            #pragma unroll
            for (int e = 0; e < NEXP; ++e) {
                float lq = accQ[e] - lseQ, lp = accP[e] - lseP;
                kl += __expf(lq) * (lq - lp);
            }
            kl_tok[t] = kl;
        }
    }
    // x -> bf16 for this block's 16 tokens
    const float* xs = x + (size_t)blockIdx.x * 16 * NEMBD;
    unsigned short* xd = xbf + (size_t)blockIdx.x * 16 * NEMBD;
    for (int i = tid; i < 16 * NEMBD / 4; i += 256) {
        float4 v = ((const float4*)xs)[i];
        ushort4 o;
        o.x = f2bf(v.x); o.y = f2bf(v.y); o.z = f2bf(v.z); o.w = f2bf(v.w);
        ((ushort4*)xd)[i] = o;
    }
}

// ---------------- offsets (64-aligned prefix) + slot init ----------------
__global__ void k_offsets(int* __restrict__ ctrl, int* __restrict__ stok,
                          float* __restrict__ sgate, int* __restrict__ srank)
{
    if (threadIdx.x == 0) {
        int off = 0;
        for (int e = 0; e < NEXP; ++e) {
            ctrl[16 + e] = off;
            off += (ctrl[e] + 63) & ~63;
        }
        ctrl[24] = off;
    }
    for (int i = threadIdx.x; i < MAXSLOT; i += 256) {
        stok[i] = 0; sgate[i] = 0.f; srank[i] = 2;   // rank=2 => pad, no store
    }
}

// ---------------- build per-expert slot lists ----------------
__global__ void k_build(const int* __restrict__ te, const float* __restrict__ tw,
                        int* __restrict__ ctrl, int* __restrict__ stok,
                        float* __restrict__ sgate, int* __restrict__ srank)
{
    int t = blockIdx.x * 256 + threadIdx.x;   // 2048 threads
    #pragma unroll
    for (int k = 0; k < 2; ++k) {
        int e = te[t * 2 + k];
        int s = atomicAdd(&ctrl[8 + e], 1);
        int flat = ctrl[16 + e] + s;
        stok[flat] = t; sgate[flat] = tw[t * 2 + k]; srank[flat] = k;
    }
}

// ---------------- GEMM1: H = relu(Xg @ Wfc[e])^2, bf16 ----------------
// 64x128 tile, 4 waves (2x2), BK=64, 16x16x32 bf16 MFMA
__global__ __launch_bounds__(256) void k_gemm1(
    const unsigned short* __restrict__ xbf, const float* __restrict__ Wfc,
    const int* __restrict__ ctrl, const int* __restrict__ slot_tok,
    unsigned short* __restrict__ H)
{
    const int NT = DFF / 128;   // 24
    int bx = blockIdx.x;
    int e  = bx / (32 * NT);
    int r  = bx % (32 * NT);
    int mt = r / NT, nt = r % NT;
    if (mt * 64 >= ctrl[e]) return;
    int base = ctrl[16 + e] + mt * 64;

    __shared__ unsigned short sA[64 * 72];    // [m][k], stride 72
    __shared__ unsigned short sB[128 * 72];   // [n][k] transposed, stride 72
    __shared__ int sTok[64];
    int tid = threadIdx.x;
    if (tid < 64) sTok[tid] = slot_tok[base + tid];
    __syncthreads();

    const float* wb = Wfc + (size_t)e * NEMBD * DFF + nt * 128;

    f32x4 acc[2][4];
    #pragma unroll
    for (int i = 0; i < 2; ++i)
        #pragma unroll
        for (int j = 0; j < 4; ++j) acc[i][j] = (f32x4){0.f, 0.f, 0.f, 0.f};

    int wave = tid >> 6, lane = tid & 63;
    int wr = wave >> 1, wc = wave & 1;

    for (int kk = 0; kk < NEMBD; kk += 64) {
        // stage A (gathered token rows, bf16, 16B chunks)
        #pragma unroll
        for (int c2 = 0; c2 < 2; ++c2) {
            int c = tid * 2 + c2;            // 0..511
            int row = c >> 3, sub = c & 7;
            int tok = sTok[row];
            const int4v* src = (const int4v*)(xbf + (size_t)tok * NEMBD + kk + sub * 8);
            *(int4v*)&sA[row * 72 + sub * 8] = *src;
        }
        // stage B transposed: thread -> n = tid&127, kg = tid>>7 (k in [kg*32, kg*32+32))
        {
            int n = tid & 127, kg = tid >> 7;
            const float* col = wb + (size_t)kk * DFF + n;
            #pragma unroll
            for (int j = 0; j < 4; ++j) {
                unsigned short u[8];
                #pragma unroll
                for (int jj = 0; jj < 8; ++jj) {
                    int k = kg * 32 + j * 8 + jj;
                    u[jj] = f2bf(col[(size_t)k * DFF]);
                }
                *(int4v*)&sB[n * 72 + kg * 32 + j * 8] = *(const int4v*)u;
            }
        }
        __syncthreads();
        #pragma unroll
        for (int kh = 0; kh < 2; ++kh) {
            short8v af[2], bfr[4];
            #pragma unroll
            for (int mr = 0; mr < 2; ++mr)
                af[mr] = *(const short8v*)&sA[(wr * 32 + mr * 16 + (lane & 15)) * 72 + kh * 32 + (lane >> 4) * 8];
            #pragma unroll
            for (int nr = 0; nr < 4; ++nr)
                bfr[nr] = *(const short8v*)&sB[(wc * 64 + nr * 16 + (lane & 15)) * 72 + kh * 32 + (lane >> 4) * 8];
            #pragma unroll
            for (int mr = 0; mr < 2; ++mr)
                #pragma unroll
                for (int nr = 0; nr < 4; ++nr)
                    acc[mr][nr] = __builtin_amdgcn_mfma_f32_16x16x32_bf16(af[mr], bfr[nr], acc[mr][nr], 0, 0, 0);
        }
        __syncthreads();
    }
    // epilogue: relu^2 -> bf16 H
    #pragma unroll
    for (int mr = 0; mr < 2; ++mr)
        #pragma unroll
        for (int nr = 0; nr < 4; ++nr) {
            int col = nt * 128 + wc * 64 + nr * 16 + (lane & 15);
            #pragma unroll
            for (int i = 0; i < 4; ++i) {
                int rowl = wr * 32 + mr * 16 + (lane >> 4) * 4 + i;
                float v = acc[mr][nr][i];
                v = v > 0.f ? v * v : 0.f;
                H[(size_t)(base + rowl) * DFF + col] = f2bf(v);
            }
        }
}

// ---------------- GEMM2: out[rank][tok] = gate * (H @ Wproj[e]) ----------------
__global__ __launch_bounds__(256) void k_gemm2(
    const unsigned short* __restrict__ H, const float* __restrict__ Wp,
    const int* __restrict__ ctrl, const int* __restrict__ slot_tok,
    const float* __restrict__ slot_gate, const int* __restrict__ slot_rank,
    float* __restrict__ obuf)
{
    const int NT = NEMBD / 128;   // 6
    int bx = blockIdx.x;
    int e  = bx / (32 * NT);
    int r  = bx % (32 * NT);
    int mt = r / NT, nt = r % NT;
    if (mt * 64 >= ctrl[e]) return;
    int base = ctrl[16 + e] + mt * 64;

    __shared__ unsigned short sA[64 * 72];
    __shared__ unsigned short sB[128 * 72];
    __shared__ int sTok[64]; __shared__ float sGate[64]; __shared__ int sRank[64];
    int tid = threadIdx.x;
    if (tid < 64) {
        sTok[tid] = slot_tok[base + tid];
        sGate[tid] = slot_gate[base + tid];
        sRank[tid] = slot_rank[base + tid];
    }
    __syncthreads();

    const float* wb = Wp + (size_t)e * DFF * NEMBD + nt * 128;

    f32x4 acc[2][4];
    #pragma unroll
    for (int i = 0; i < 2; ++i)
        #pragma unroll
        for (int j = 0; j < 4; ++j) acc[i][j] = (f32x4){0.f, 0.f, 0.f, 0.f};

    int wave = tid >> 6, lane = tid & 63;
    int wr = wave >> 1, wc = wave & 1;

    for (int kk = 0; kk < DFF; kk += 64) {
        #pragma unroll
        for (int c2 = 0; c2 < 2; ++c2) {
            int c = tid * 2 + c2;
            int row = c >> 3, sub = c & 7;
            const int4v* src = (const int4v*)(H + (size_t)(base + row) * DFF + kk + sub * 8);
            *(int4v*)&sA[row * 72 + sub * 8] = *src;
        }
        {
            int n = tid & 127, kg = tid >> 7;
            const float* col = wb + (size_t)kk * NEMBD + n;
            #pragma unroll
            for (int j = 0; j < 4; ++j) {
                unsigned short u[8];
                #pragma unroll
                for (int jj = 0; jj < 8; ++jj) {
                    int k = kg * 32 + j * 8 + jj;
                    u[jj] = f2bf(col[(size_t)k * NEMBD]);
                }
                *(int4v*)&sB[n * 72 + kg * 32 + j * 8] = *(const int4v*)u;
            }
        }
        __syncthreads();
        #pragma unroll
        for (int kh = 0; kh < 2; ++kh) {
            short8v af[2], bfr[4];
            #pragma unroll
            for (int mr = 0; mr < 2; ++mr)
                af[mr] = *(const short8v*)&sA[(wr * 32 + mr * 16 + (lane & 15)) * 72 + kh * 32 + (lane >> 4) * 8];
            #pragma unroll
            for (int nr = 0; nr < 4; ++nr)
                bfr[nr] = *(const short8v*)&sB[(wc * 64 + nr * 16 + (lane & 15)) * 72 + kh * 32 + (lane >> 4) * 8];
            #pragma unroll
            for (int mr = 0; mr < 2; ++mr)
                #pragma unroll
                for (int nr = 0; nr < 4; ++nr)
                    acc[mr][nr] = __builtin_amdgcn_mfma_f32_16x16x32_bf16(af[mr], bfr[nr], acc[mr][nr], 0, 0, 0);
        }
        __syncthreads();
    }
    #pragma unroll
    for (int mr = 0; mr < 2; ++mr)
        #pragma unroll
        for (int nr = 0; nr < 4; ++nr) {
            int col = nt * 128 + wc * 64 + nr * 16 + (lane & 15);
            #pragma unroll
            for (int i = 0; i < 4; ++i) {
                int rowl = wr * 32 + mr * 16 + (lane >> 4) * 4 + i;
                int rk = sRank[rowl];
                if (rk < 2) {
                    obuf[(size_t)rk * NTOK * NEMBD + (size_t)sTok[rowl] * NEMBD + col] =
                        sGate[rowl] * acc[mr][nr][i];
                }
            }
        }
}

// ---------------- combine rank buffers ----------------
__global__ void k_combine(const float4* __restrict__ ob, float4* __restrict__ out)
{
    int i = blockIdx.x * 256 + threadIdx.x;   // 393216 total
    float4 a = ob[i], b = ob[i + NTOK * NEMBD / 4];
    float4 o; o.x = a.x + b.x; o.y = a.y + b.y; o.z = a.z + b.z; o.w = a.w + b.w;
    out[i] = o;
}

// ---------------- aux loss (deterministic single-block reduce) ----------------
__global__ void k_aux(const float* __restrict__ gates, const float* __restrict__ kl_tok,
                      const int* __restrict__ ctrl, float* __restrict__ out_aux)
{
    __shared__ float sred[256];
    int tid = threadIdx.x;
    float p[NEXP]; float kls = 0.f;
    #pragma unroll
    for (int e = 0; e < NEXP; ++e) p[e] = 0.f;
    for (int t = tid; t < NTOK; t += 256) {
        #pragma unroll
        for (int e = 0; e < NEXP; ++e) p[e] += gates[t * NEXP + e];
        kls += kl_tok[t];
    }
    float Ps[NEXP];
    for (int e = 0; e < NEXP; ++e) {
        sred[tid] = p[e]; __syncthreads();
        for (int s = 128; s; s >>= 1) { if (tid < s) sred[tid] += sred[tid + s]; __syncthreads(); }
        if (tid == 0) Ps[e] = sred[0];
        __syncthreads();
    }
    sred[tid] = kls; __syncthreads();
    for (int s = 128; s; s >>= 1) { if (tid < s) sred[tid] += sred[tid + s]; __syncthreads(); }
    if (tid == 0) {
        float kl_mean = sred[0] / (float)NTOK;
        float lb = 0.f;
        for (int e = 0; e < NEXP; ++e)
            lb += ((float)ctrl[e] / (float)(NTOK * 2)) * (Ps[e] / (float)NTOK);
        lb *= (float)NEXP * 0.01f;
        out_aux[0] = lb + kl_mean;
    }
}

extern "C" void kernel_launch(void* const* d_in, const int* in_sizes, int n_in,
                              void* d_out, int out_size, void* d_ws, size_t ws_size,
                              hipStream_t stream) {
    const float* x   = (const float*)d_in[0];
    const float* WgP = (const float*)d_in[1];
    const float* WgQ = (const float*)d_in[2];
    const float* Wfc = (const float*)d_in[3];
    const float* Wpj = (const float*)d_in[4];
    float* out = (float*)d_out;

    char* ws = (char*)d_ws;
    unsigned short* xbf  = (unsigned short*)(ws + WS_XBF);
    float* gates = (float*)(ws + WS_GATES);
    int*   te    = (int*)(ws + WS_TE);
    float* tw    = (float*)(ws + WS_TW);
    float* klt   = (float*)(ws + WS_KL);
    int*   ctrl  = (int*)(ws + WS_CTRL);
    int*   stok  = (int*)(ws + WS_STOK);
    float* sgate = (float*)(ws + WS_SGATE);
    int*   srank = (int*)(ws + WS_SRANK);
    unsigned short* H = (unsigned short*)(ws + WS_H);
    float* obuf  = (float*)(ws + WS_OUT);

    hipMemsetAsync(ctrl, 0, 128, stream);
    k_router<<<128, 256, 0, stream>>>(x, WgP, WgQ, xbf, gates, te, tw, klt, ctrl);
    k_offsets<<<1, 256, 0, stream>>>(ctrl, stok, sgate, srank);
    k_build<<<8, 256, 0, stream>>>(te, tw, ctrl, stok, sgate, srank);
    k_gemm1<<<NEXP * 32 * (DFF / 128), 256, 0, stream>>>(xbf, Wfc, ctrl, stok, H);
    k_gemm2<<<NEXP * 32 * (NEMBD / 128), 256, 0, stream>>>(H, Wpj, ctrl, stok, sgate, srank, obuf);
    k_combine<<<NTOK * NEMBD / 4 / 256, 256, 0, stream>>>((const float4*)obuf, (float4*)out);
    k_aux<<<1, 256, 0, stream>>>(gates, klt, ctrl, out + (size_t)NTOK * NEMBD);
}

// Round 2
// 250.412 us; speedup vs baseline: 1.6639x; 1.6639x over previous
//
#include <hip/hip_runtime.h>
#include <hip/hip_bf16.h>

typedef __attribute__((ext_vector_type(8))) short short8v;   // 8 bf16
typedef __attribute__((ext_vector_type(4))) float f32x4;
typedef __attribute__((ext_vector_type(4))) int int4v;

#define NTOK  2048
#define NEMBD 768
#define DFF   3072
#define NEXP  8
#define MAXSLOT 5120          // 128-aligned per-expert regions, sum <= 4992
#define NT1 24                // DFF/128
#define NT2 6                 // NEMBD/128
#define MAXT1 40              // max 128-row tiles (bound 39)
#define MAXT2 80              // max 64-row tiles (bound 78)

// ---- workspace layout (bytes) ----
#define WS_XBF   0                                   // ushort [2048][768]
#define WS_GATES (WS_XBF + (size_t)NTOK*NEMBD*2)     // float  [2048][8]
#define WS_TE    (WS_GATES + NTOK*8*4)               // int    [2048][2]
#define WS_TW    (WS_TE + NTOK*2*4)                  // float  [2048][2]
#define WS_KL    (WS_TW + NTOK*2*4)                  // float  [2048]
#define WS_CTRL  (WS_KL + NTOK*4)                    // int[512]
#define WS_STOK  (WS_CTRL + 2048)                    // int    [MAXSLOT]
#define WS_SGATE (WS_STOK + MAXSLOT*4)               // float  [MAXSLOT]
#define WS_SRANK (WS_SGATE + MAXSLOT*4)              // int    [MAXSLOT]
#define WS_WFCT  (WS_SRANK + MAXSLOT*4)              // ushort [8][3072][768]
#define WS_WPT   (WS_WFCT + (size_t)NEXP*DFF*NEMBD*2)// ushort [8][768][3072]
#define WS_H     (WS_WPT + (size_t)NEXP*NEMBD*DFF*2) // ushort [MAXSLOT][3072]
#define WS_OUT   (WS_H + (size_t)MAXSLOT*DFF*2)      // float  [2][2048][768]
// total ~123 MB

__device__ __forceinline__ unsigned short f2bf(float f) {
    union { float f; unsigned u; } v; v.f = f;
    unsigned r = v.u + 0x7fffu + ((v.u >> 16) & 1u);   // RNE
    return (unsigned short)(r >> 16);
}

__device__ __forceinline__ void gload16(const void* g, void* l) {
    __builtin_amdgcn_global_load_lds(
        (const __attribute__((address_space(1))) void*)g,
        (__attribute__((address_space(3))) void*)l, 16, 0, 0);
}

// ---------------- router: logits (fp32), softmax, top2, KL, x->bf16 ----------------
__global__ __launch_bounds__(256) void k_router(
    const float* __restrict__ x, const float* __restrict__ WgP, const float* __restrict__ WgQ,
    unsigned short* __restrict__ xbf, float* __restrict__ gates,
    int* __restrict__ te, float* __restrict__ tw, float* __restrict__ kl_tok,
    int* __restrict__ ctrl)
{
    __shared__ float sWp[NEMBD * NEXP];
    __shared__ float sWq[NEMBD * NEXP];
    int tid = threadIdx.x;
    for (int i = tid; i < NEMBD * NEXP; i += 256) { sWp[i] = WgP[i]; sWq[i] = WgQ[i]; }
    __syncthreads();

    int wave = tid >> 6, lane = tid & 63;
    for (int it = 0; it < 4; ++it) {
        int t = blockIdx.x * 16 + it * 4 + wave;
        int b = t >> 10, l = t & 1023;
        int lf = l + 2; if (lf > 1023) lf = 1023;
        const float* xr = x + (size_t)t * NEMBD;
        const float* xf = x + ((size_t)((b << 10) + lf)) * NEMBD;
        float accP[NEXP], accQ[NEXP];
        #pragma unroll
        for (int e = 0; e < NEXP; ++e) { accP[e] = 0.f; accQ[e] = 0.f; }
        for (int k = lane; k < NEMBD; k += 64) {
            float xv = xr[k], xfv = xf[k];
            #pragma unroll
            for (int e = 0; e < NEXP; ++e) {
                accP[e] += xv  * sWp[k * NEXP + e];
                accQ[e] += xfv * sWq[k * NEXP + e];
            }
        }
        #pragma unroll
        for (int e = 0; e < NEXP; ++e) {
            #pragma unroll
            for (int off = 32; off; off >>= 1) {
                accP[e] += __shfl_xor(accP[e], off);
                accQ[e] += __shfl_xor(accQ[e], off);
            }
        }
        if (lane == 0) {
            float mq = accQ[0], mp = accP[0];
            #pragma unroll
            for (int e = 1; e < NEXP; ++e) { mq = fmaxf(mq, accQ[e]); mp = fmaxf(mp, accP[e]); }
            float g[NEXP], se = 0.f, sp = 0.f;
            #pragma unroll
            for (int e = 0; e < NEXP; ++e) {
                g[e] = __expf(accQ[e] - mq); se += g[e];
                sp += __expf(accP[e] - mp);
            }
            float inv_se = 1.f / se;
            #pragma unroll
            for (int e = 0; e < NEXP; ++e) gates[t * NEXP + e] = g[e] * inv_se;
            int e0 = 0;
            #pragma unroll
            for (int e = 1; e < NEXP; ++e) if (g[e] > g[e0]) e0 = e;
            int e1 = (e0 == 0) ? 1 : 0;
            #pragma unroll
            for (int e = 0; e < NEXP; ++e) if (e != e0 && g[e] > g[e1]) e1 = e;
            float s2 = g[e0] + g[e1];
            te[t * 2] = e0; te[t * 2 + 1] = e1;
            tw[t * 2] = g[e0] / s2; tw[t * 2 + 1] = g[e1] / s2;
            atomicAdd(&ctrl[e0], 1); atomicAdd(&ctrl[e1], 1);
            float lseQ = mq + logf(se), lseP = mp + logf(sp);
            float kl = 0.f;
            #pragma unroll
            for (int e = 0; e < NEXP; ++e) {
                float lq = accQ[e] - lseQ, lp = accP[e] - lseP;
                kl += __expf(lq) * (lq - lp);
            }
            kl_tok[t] = kl;
        }
    }
    const float* xs = x + (size_t)blockIdx.x * 16 * NEMBD;
    unsigned short* xd = xbf + (size_t)blockIdx.x * 16 * NEMBD;
    for (int i = tid; i < 16 * NEMBD / 4; i += 256) {
        float4 v = ((const float4*)xs)[i];
        ushort4 o;
        o.x = f2bf(v.x); o.y = f2bf(v.y); o.z = f2bf(v.z); o.w = f2bf(v.w);
        ((ushort4*)xd)[i] = o;
    }
}

// ---------------- transpose+convert: in [E][R][C] f32 -> out [E][C][R] bf16 ----------------
__global__ __launch_bounds__(256) void k_transpose(
    const float* __restrict__ in, unsigned short* __restrict__ out,
    int R, int C, int tilesR, int tilesC)
{
    int bx = blockIdx.x;
    int per = tilesR * tilesC;
    int e = bx / per, rem = bx % per;
    int rt = rem / tilesC, ct = rem % tilesC;
    __shared__ unsigned short sT[64][72];
    const float* src = in + ((size_t)e * R + rt * 64) * C + ct * 64;
    int tid = threadIdx.x;
    #pragma unroll
    for (int i = 0; i < 4; ++i) {
        int idx = tid + i * 256;
        int r = idx >> 4, c4 = idx & 15;
        float4 v = *(const float4*)&src[(size_t)r * C + c4 * 4];
        ushort4 o; o.x = f2bf(v.x); o.y = f2bf(v.y); o.z = f2bf(v.z); o.w = f2bf(v.w);
        *(ushort4*)&sT[r][c4 * 4] = o;
    }
    __syncthreads();
    unsigned short* dst = out + ((size_t)e * C + ct * 64) * R + rt * 64;
    #pragma unroll
    for (int i = 0; i < 2; ++i) {
        int idx = tid + i * 256;
        int oc = idx >> 3, j = idx & 7;
        unsigned short u[8];
        #pragma unroll
        for (int s = 0; s < 8; ++s) u[s] = sT[j * 8 + s][oc];
        *(int4v*)&dst[(size_t)oc * R + j * 8] = *(const int4v*)u;
    }
}

// ---------------- offsets (128-aligned), tile tables, slot init ----------------
// ctrl: [0..7] counts, [8..15] cursors, [16..23] expert base, [24] total,
//       [25] ntiles1, [26] ntiles2, [64..103] t1 (e<<16|mt), [128..207] t2
__global__ void k_offsets(int* __restrict__ ctrl, int* __restrict__ stok,
                          float* __restrict__ sgate, int* __restrict__ srank)
{
    if (threadIdx.x == 0) {
        int off = 0, n1 = 0, n2 = 0;
        for (int e = 0; e < NEXP; ++e) {
            ctrl[16 + e] = off;
            int t128 = (ctrl[e] + 127) >> 7;
            for (int m = 0; m < t128; ++m)     ctrl[64 + n1++]  = (e << 16) | m;
            for (int m = 0; m < 2 * t128; ++m) ctrl[128 + n2++] = (e << 16) | m;
            off += t128 << 7;
        }
        ctrl[24] = off; ctrl[25] = n1; ctrl[26] = n2;
    }
    for (int i = threadIdx.x; i < MAXSLOT; i += 256) {
        stok[i] = 0; sgate[i] = 0.f; srank[i] = 2;
    }
}

// ---------------- build per-expert slot lists ----------------
__global__ void k_build(const int* __restrict__ te, const float* __restrict__ tw,
                        int* __restrict__ ctrl, int* __restrict__ stok,
                        float* __restrict__ sgate, int* __restrict__ srank)
{
    int t = blockIdx.x * 256 + threadIdx.x;
    #pragma unroll
    for (int k = 0; k < 2; ++k) {
        int e = te[t * 2 + k];
        int s = atomicAdd(&ctrl[8 + e], 1);
        int flat = ctrl[16 + e] + s;
        stok[flat] = t; sgate[flat] = tw[t * 2 + k]; srank[flat] = k;
    }
}

// ---------------- GEMM1: H = relu(Xg @ WfcT^T)^2, 128x128 tile, BK=64 ----------------
__global__ __launch_bounds__(256) void k_gemm1(
    const unsigned short* __restrict__ xbf, const unsigned short* __restrict__ WfcT,
    const int* __restrict__ ctrl, const int* __restrict__ slot_tok,
    unsigned short* __restrict__ H)
{
    int bx = blockIdx.x;                      // grid = MAXT1*NT1 = 960
    int swz = (bx & 7) * (MAXT1 * NT1 / 8) + (bx >> 3);
    int nt = swz / MAXT1, tI = swz % MAXT1;
    if (tI >= ctrl[25]) return;
    int pk = ctrl[64 + tI];
    int e = pk >> 16, mt = pk & 0xffff;
    int base = ctrl[16 + e] + (mt << 7);

    __shared__ unsigned short sAB[2 * 128 * 64];   // sA | sB, reused as sC[128][128]
    unsigned short* sA = sAB;
    unsigned short* sB = sAB + 128 * 64;

    int tid = threadIdx.x, w = tid >> 6, lane = tid & 63;
    int wr = w >> 1, wc = w & 1;

    const unsigned short* wfc = WfcT + ((size_t)e * DFF + nt * 128) * NEMBD;
    const unsigned short* aptr[4]; const unsigned short* bptr[4];
    #pragma unroll
    for (int i = 0; i < 4; ++i) {
        int r = i * 32 + w * 8 + (lane >> 3);
        aptr[i] = xbf + (size_t)slot_tok[base + r] * NEMBD + (lane & 7) * 8;
        bptr[i] = wfc + (size_t)r * NEMBD + (lane & 7) * 8;
    }

    f32x4 acc[4][4];
    #pragma unroll
    for (int i = 0; i < 4; ++i)
        #pragma unroll
        for (int j = 0; j < 4; ++j) acc[i][j] = (f32x4){0.f, 0.f, 0.f, 0.f};

    for (int kk = 0; kk < NEMBD; kk += 64) {
        #pragma unroll
        for (int i = 0; i < 4; ++i) {
            gload16(aptr[i] + kk, &sA[(i * 256 + w * 64) * 8]);
            gload16(bptr[i] + kk, &sB[(i * 256 + w * 64) * 8]);
        }
        __syncthreads();
        #pragma unroll
        for (int kh = 0; kh < 2; ++kh) {
            short8v af[4], bfv[4];
            #pragma unroll
            for (int m = 0; m < 4; ++m)
                af[m] = *(const short8v*)&sA[(wr * 64 + m * 16 + (lane & 15)) * 64 + kh * 32 + (lane >> 4) * 8];
            #pragma unroll
            for (int n = 0; n < 4; ++n)
                bfv[n] = *(const short8v*)&sB[(wc * 64 + n * 16 + (lane & 15)) * 64 + kh * 32 + (lane >> 4) * 8];
            #pragma unroll
            for (int m = 0; m < 4; ++m)
                #pragma unroll
                for (int n = 0; n < 4; ++n)
                    acc[m][n] = __builtin_amdgcn_mfma_f32_16x16x32_bf16(af[m], bfv[n], acc[m][n], 0, 0, 0);
        }
        __syncthreads();
    }

    // epilogue: relu^2 -> bf16, repack via LDS for 16B coalesced stores
    unsigned short* sC = sAB;   // [128][128]
    #pragma unroll
    for (int m = 0; m < 4; ++m)
        #pragma unroll
        for (int n = 0; n < 4; ++n) {
            int col = wc * 64 + n * 16 + (lane & 15);
            #pragma unroll
            for (int i = 0; i < 4; ++i) {
                int row = wr * 64 + m * 16 + (lane >> 4) * 4 + i;
                float v = acc[m][n][i];
                v = v > 0.f ? v * v : 0.f;
                sC[row * 128 + col] = f2bf(v);
            }
        }
    __syncthreads();
    #pragma unroll
    for (int it = 0; it < 8; ++it) {
        int idx = tid + it * 256;
        int row = idx >> 4, j = idx & 15;
        *(int4v*)&H[(size_t)(base + row) * DFF + nt * 128 + j * 8] =
            *(const int4v*)&sC[row * 128 + j * 8];
    }
}

// ---------------- GEMM2: obuf[rank][tok] = gate * (H @ WpT^T), 64x128 tile ----------------
__global__ __launch_bounds__(256) void k_gemm2(
    const unsigned short* __restrict__ H, const unsigned short* __restrict__ WpT,
    const int* __restrict__ ctrl, const int* __restrict__ slot_tok,
    const float* __restrict__ slot_gate, const int* __restrict__ slot_rank,
    float* __restrict__ obuf)
{
    int bx = blockIdx.x;                      // grid = MAXT2*NT2 = 480
    int swz = (bx & 7) * (MAXT2 * NT2 / 8) + (bx >> 3);
    int nt = swz / MAXT2, tI = swz % MAXT2;
    if (tI >= ctrl[26]) return;
    int pk = ctrl[128 + tI];
    int e = pk >> 16, mt = pk & 0xffff;
    int base = ctrl[16 + e] + (mt << 6);

    __shared__ unsigned short sA[64 * 64];    // 8 KB
    __shared__ unsigned short sB[128 * 64];   // 16 KB
    __shared__ int sTok[64]; __shared__ float sGate[64]; __shared__ int sRank[64];

    int tid = threadIdx.x, w = tid >> 6, lane = tid & 63;
    int wr = w >> 1, wc = w & 1;
    if (tid < 64) {
        sTok[tid] = slot_tok[base + tid];
        sGate[tid] = slot_gate[base + tid];
        sRank[tid] = slot_rank[base + tid];
    }

    const unsigned short* wp = WpT + ((size_t)e * NEMBD + nt * 128) * DFF;
    const unsigned short* aptr[2]; const unsigned short* bptr[4];
    #pragma unroll
    for (int i = 0; i < 2; ++i) {
        int r = i * 32 + w * 8 + (lane >> 3);
        aptr[i] = H + (size_t)(base + r) * DFF + (lane & 7) * 8;
    }
    #pragma unroll
    for (int i = 0; i < 4; ++i) {
        int r = i * 32 + w * 8 + (lane >> 3);
        bptr[i] = wp + (size_t)r * DFF + (lane & 7) * 8;
    }

    f32x4 acc[2][4];
    #pragma unroll
    for (int i = 0; i < 2; ++i)
        #pragma unroll
        for (int j = 0; j < 4; ++j) acc[i][j] = (f32x4){0.f, 0.f, 0.f, 0.f};

    for (int kk = 0; kk < DFF; kk += 64) {
        #pragma unroll
        for (int i = 0; i < 2; ++i)
            gload16(aptr[i] + kk, &sA[(i * 256 + w * 64) * 8]);
        #pragma unroll
        for (int i = 0; i < 4; ++i)
            gload16(bptr[i] + kk, &sB[(i * 256 + w * 64) * 8]);
        __syncthreads();
        #pragma unroll
        for (int kh = 0; kh < 2; ++kh) {
            short8v af[2], bfv[4];
            #pragma unroll
            for (int m = 0; m < 2; ++m)
                af[m] = *(const short8v*)&sA[(wr * 32 + m * 16 + (lane & 15)) * 64 + kh * 32 + (lane >> 4) * 8];
            #pragma unroll
            for (int n = 0; n < 4; ++n)
                bfv[n] = *(const short8v*)&sB[(wc * 64 + n * 16 + (lane & 15)) * 64 + kh * 32 + (lane >> 4) * 8];
            #pragma unroll
            for (int m = 0; m < 2; ++m)
                #pragma unroll
                for (int n = 0; n < 4; ++n)
                    acc[m][n] = __builtin_amdgcn_mfma_f32_16x16x32_bf16(af[m], bfv[n], acc[m][n], 0, 0, 0);
        }
        __syncthreads();
    }

    #pragma unroll
    for (int m = 0; m < 2; ++m)
        #pragma unroll
        for (int n = 0; n < 4; ++n) {
            int col = nt * 128 + wc * 64 + n * 16 + (lane & 15);
            #pragma unroll
            for (int i = 0; i < 4; ++i) {
                int row = wr * 32 + m * 16 + (lane >> 4) * 4 + i;
                int rk = sRank[row];
                if (rk < 2) {
                    obuf[(size_t)rk * NTOK * NEMBD + (size_t)sTok[row] * NEMBD + col] =
                        sGate[row] * acc[m][n][i];
                }
            }
        }
}

// ---------------- combine rank buffers ----------------
__global__ void k_combine(const float4* __restrict__ ob, float4* __restrict__ out)
{
    int i = blockIdx.x * 256 + threadIdx.x;
    float4 a = ob[i], b = ob[i + NTOK * NEMBD / 4];
    float4 o; o.x = a.x + b.x; o.y = a.y + b.y; o.z = a.z + b.z; o.w = a.w + b.w;
    out[i] = o;
}

// ---------------- aux loss ----------------
__global__ void k_aux(const float* __restrict__ gates, const float* __restrict__ kl_tok,
                      const int* __restrict__ ctrl, float* __restrict__ out_aux)
{
    __shared__ float sred[256];
    int tid = threadIdx.x;
    float p[NEXP]; float kls = 0.f;
    #pragma unroll
    for (int e = 0; e < NEXP; ++e) p[e] = 0.f;
    for (int t = tid; t < NTOK; t += 256) {
        #pragma unroll
        for (int e = 0; e < NEXP; ++e) p[e] += gates[t * NEXP + e];
        kls += kl_tok[t];
    }
    float Ps[NEXP];
    for (int e = 0; e < NEXP; ++e) {
        sred[tid] = p[e]; __syncthreads();
        for (int s = 128; s; s >>= 1) { if (tid < s) sred[tid] += sred[tid + s]; __syncthreads(); }
        if (tid == 0) Ps[e] = sred[0];
        __syncthreads();
    }
    sred[tid] = kls; __syncthreads();
    for (int s = 128; s; s >>= 1) { if (tid < s) sred[tid] += sred[tid + s]; __syncthreads(); }
    if (tid == 0) {
        float kl_mean = sred[0] / (float)NTOK;
        float lb = 0.f;
        for (int e = 0; e < NEXP; ++e)
            lb += ((float)ctrl[e] / (float)(NTOK * 2)) * (Ps[e] / (float)NTOK);
        lb *= (float)NEXP * 0.01f;
        out_aux[0] = lb + kl_mean;
    }
}

extern "C" void kernel_launch(void* const* d_in, const int* in_sizes, int n_in,
                              void* d_out, int out_size, void* d_ws, size_t ws_size,
                              hipStream_t stream) {
    const float* x   = (const float*)d_in[0];
    const float* WgP = (const float*)d_in[1];
    const float* WgQ = (const float*)d_in[2];
    const float* Wfc = (const float*)d_in[3];
    const float* Wpj = (const float*)d_in[4];
    float* out = (float*)d_out;

    char* ws = (char*)d_ws;
    unsigned short* xbf  = (unsigned short*)(ws + WS_XBF);
    float* gates = (float*)(ws + WS_GATES);
    int*   te    = (int*)(ws + WS_TE);
    float* tw    = (float*)(ws + WS_TW);
    float* klt   = (float*)(ws + WS_KL);
    int*   ctrl  = (int*)(ws + WS_CTRL);
    int*   stok  = (int*)(ws + WS_STOK);
    float* sgate = (float*)(ws + WS_SGATE);
    int*   srank = (int*)(ws + WS_SRANK);
    unsigned short* WfcT = (unsigned short*)(ws + WS_WFCT);
    unsigned short* WpT  = (unsigned short*)(ws + WS_WPT);
    unsigned short* H    = (unsigned short*)(ws + WS_H);
    float* obuf  = (float*)(ws + WS_OUT);

    hipMemsetAsync(ctrl, 0, 64, stream);
    k_router<<<128, 256, 0, stream>>>(x, WgP, WgQ, xbf, gates, te, tw, klt, ctrl);
    // W_fc [8][768][3072] -> WfcT [8][3072][768]
    k_transpose<<<NEXP * 12 * 48, 256, 0, stream>>>(Wfc, WfcT, NEMBD, DFF, 12, 48);
    // W_proj [8][3072][768] -> WpT [8][768][3072]
    k_transpose<<<NEXP * 48 * 12, 256, 0, stream>>>(Wpj, WpT, DFF, NEMBD, 48, 12);
    k_offsets<<<1, 256, 0, stream>>>(ctrl, stok, sgate, srank);
    k_build<<<8, 256, 0, stream>>>(te, tw, ctrl, stok, sgate, srank);
    k_gemm1<<<MAXT1 * NT1, 256, 0, stream>>>(xbf, WfcT, ctrl, stok, H);
    k_gemm2<<<MAXT2 * NT2, 256, 0, stream>>>(H, WpT, ctrl, stok, sgate, srank, obuf);
    k_combine<<<NTOK * NEMBD / 4 / 256, 256, 0, stream>>>((const float4*)obuf, (float4*)out);
    k_aux<<<1, 256, 0, stream>>>(gates, klt, ctrl, out + (size_t)NTOK * NEMBD);
}